// Round 2
// baseline (1460.315 us; speedup 1.0000x reference)
//
#include <hip/hip_runtime.h>
#include <hip/hip_bf16.h>
#include <cstdint>

// MoE feed-forward, routed top-2 of 8 experts.
// B=2 S=2048 D=1024 F=2048 E=8 K=2.
// R1: async global_load_lds staging (m97 pattern), gemm2 scratch+combine (no atomics),
//     grid-stride m-loop sized to expected load, launch_bounds(256,4).

#define Dd 1024
#define Ff 2048
#define Ee 8
#define TOK 4096
#define PAIRS 8192

typedef __attribute__((ext_vector_type(8))) short short8;
typedef __attribute__((ext_vector_type(4))) float floatx4;

__device__ __forceinline__ unsigned short f2bf(float f) {
    unsigned int u = __float_as_uint(f);
    unsigned int r = (u + 0x7FFFu + ((u >> 16) & 1u)) >> 16;
    return (unsigned short)r;
}

// async 16B/lane global->LDS. lds ptr must be wave-uniform; lane i lands at lds + i*16B.
__device__ __forceinline__ void gload16(const unsigned short* g, unsigned short* l) {
    __builtin_amdgcn_global_load_lds(
        (const __attribute__((address_space(1))) unsigned int*)g,
        (__attribute__((address_space(3))) unsigned int*)l,
        16, 0, 0);
}

// ---------------- zero meta (+ optionally out) ----------------
__global__ void zero_kernel(float* __restrict__ out, int n4, int* __restrict__ meta) {
    int i = blockIdx.x * blockDim.x + threadIdx.x;
    if (i < n4) reinterpret_cast<float4*>(out)[i] = make_float4(0.f, 0.f, 0.f, 0.f);
    if (i < 32) meta[i] = 0;   // meta: [0..7]=counts [8..15]=cursor [16..23]=base
}

// ---------------- gating: fp32 scores, top-2, softmax ----------------
__global__ void gating_kernel(const float* __restrict__ x, const float* __restrict__ Wg,
                              int* __restrict__ tok_idx, float* __restrict__ tok_prob,
                              int* __restrict__ meta) {
    int lane = threadIdx.x & 63;
    int w = threadIdx.x >> 6;
    int t = blockIdx.x * 4 + w;

    float xr[16];
    const float* xp = x + (size_t)t * Dd;
#pragma unroll
    for (int i = 0; i < 16; i++) xr[i] = xp[lane + i * 64];

    float sc[Ee];
    for (int e = 0; e < Ee; e++) {
        const float* wp = Wg + (size_t)e * Dd;
        float p = 0.f;
#pragma unroll
        for (int i = 0; i < 16; i++) p += xr[i] * wp[lane + i * 64];
        for (int off = 32; off > 0; off >>= 1) p += __shfl_xor(p, off);
        sc[e] = p;
    }
    if (lane == 0) {
        int e1 = 0, e2 = 0;
        float b1 = -1e30f, b2 = -1e30f;
        for (int e = 0; e < Ee; e++) {
            float s = sc[e];
            if (s > b1) { b2 = b1; e2 = e1; b1 = s; e1 = e; }
            else if (s > b2) { b2 = s; e2 = e; }
        }
        float p1 = 1.f / (1.f + expf(b2 - b1));
        float p2 = 1.f - p1;
        tok_idx[t * 2 + 0] = e1;
        tok_idx[t * 2 + 1] = e2;
        tok_prob[t * 2 + 0] = p1;
        tok_prob[t * 2 + 1] = p2;
        atomicAdd(&meta[e1], 1);
        atomicAdd(&meta[e2], 1);
    }
}

// ---------------- exclusive scan of counts -> base ----------------
__global__ void scan_kernel(int* __restrict__ meta) {
    int b = 0;
    for (int e = 0; e < Ee; e++) { meta[16 + e] = b; b += meta[e]; }
}

// ---------------- scatter tokens into per-expert lists (+ inverse map) ----------------
__global__ void scatter_kernel(const int* __restrict__ tok_idx, const float* __restrict__ tok_prob,
                               int* __restrict__ meta,
                               int* __restrict__ list_tok, float* __restrict__ list_prob,
                               int* __restrict__ pos_of) {
    int t = blockIdx.x * blockDim.x + threadIdx.x;
    if (t >= TOK) return;
    for (int k = 0; k < 2; k++) {
        int e = tok_idx[t * 2 + k];
        int pos = meta[16 + e] + atomicAdd(&meta[8 + e], 1);
        list_tok[pos] = t;
        list_prob[pos] = tok_prob[t * 2 + k];
        pos_of[t * 2 + k] = pos;
    }
}

// ---------------- fp32 -> bf16 convert ----------------
__global__ void cvt_kernel(const float* __restrict__ src, unsigned short* __restrict__ dst, int n4) {
    int i = blockIdx.x * blockDim.x + threadIdx.x;
    if (i >= n4) return;
    float4 v = reinterpret_cast<const float4*>(src)[i];
    uint2 o;
    o.x = (unsigned)f2bf(v.x) | ((unsigned)f2bf(v.y) << 16);
    o.y = (unsigned)f2bf(v.z) | ((unsigned)f2bf(v.w) << 16);
    reinterpret_cast<uint2*>(dst)[i] = o;
}

// ---------------- manual fp32->bf16 LDS staging (fallback path only) ----------------
__device__ __forceinline__ void stage16(unsigned short* dst, const float* src) {
    const float4* s = reinterpret_cast<const float4*>(src);
    float4 v0 = s[0], v1 = s[1], v2 = s[2], v3 = s[3];
    uint4 o0, o1;
    o0.x = (unsigned)f2bf(v0.x) | ((unsigned)f2bf(v0.y) << 16);
    o0.y = (unsigned)f2bf(v0.z) | ((unsigned)f2bf(v0.w) << 16);
    o0.z = (unsigned)f2bf(v1.x) | ((unsigned)f2bf(v1.y) << 16);
    o0.w = (unsigned)f2bf(v1.z) | ((unsigned)f2bf(v1.w) << 16);
    o1.x = (unsigned)f2bf(v2.x) | ((unsigned)f2bf(v2.y) << 16);
    o1.y = (unsigned)f2bf(v2.z) | ((unsigned)f2bf(v2.w) << 16);
    o1.z = (unsigned)f2bf(v3.x) | ((unsigned)f2bf(v3.y) << 16);
    o1.w = (unsigned)f2bf(v3.z) | ((unsigned)f2bf(v3.w) << 16);
    uint4* d = reinterpret_cast<uint4*>(dst);
    d[0] = o0;
    d[1] = o1;
}

// ---------------- GEMM1: hidden = silu(x W1^T) * (x W2^T), routed ----------------
template <typename WT>
__global__ __launch_bounds__(256, 4) void gemm1_kernel(
    const unsigned short* __restrict__ xb,
    const WT* __restrict__ W1, const WT* __restrict__ W2,
    unsigned short* __restrict__ hidden,
    const int* __restrict__ list_tok, const int* __restrict__ meta) {
    constexpr bool BF = (sizeof(WT) == 2);
    int e = blockIdx.z;
    int cnt = meta[e];
    int bs = meta[16 + e];
    int n0 = blockIdx.x * 128;

    __shared__ unsigned short sA[128 * 32];
    __shared__ unsigned short sB1[128 * 32];
    __shared__ unsigned short sB2[128 * 32];

    int tid = threadIdx.x;
    int lane = tid & 63;
    int w = tid >> 6;
    int wm = w >> 1, wn = w & 1;
    int lane15 = lane & 15, quad = lane >> 4;

    // async staging geometry: issue j of wave w covers rows [w*32+j*16, +16)
    int jr = w * 32 + (lane >> 2);   // row for issue 0 (+16 for issue 1)
    int c8 = (lane & 3) * 8;         // ushort offset of this lane's 16B chunk
    unsigned short* ldsA0 = sA + w * 1024;
    unsigned short* ldsA1 = sA + w * 1024 + 512;
    unsigned short* ldsB10 = sB1 + w * 1024;
    unsigned short* ldsB11 = sB1 + w * 1024 + 512;
    unsigned short* ldsB20 = sB2 + w * 1024;
    unsigned short* ldsB21 = sB2 + w * 1024 + 512;

    const WT *b1r0 = nullptr, *b1r1 = nullptr, *b2r0 = nullptr, *b2r1 = nullptr;
    const WT *b1m = nullptr, *b2m = nullptr;
    unsigned short *sB1w = nullptr, *sB2w = nullptr;
    if constexpr (BF) {
        b1r0 = W1 + ((size_t)e * Ff + n0 + jr) * Dd + c8;
        b1r1 = W1 + ((size_t)e * Ff + n0 + jr + 16) * Dd + c8;
        b2r0 = W2 + ((size_t)e * Ff + n0 + jr) * Dd + c8;
        b2r1 = W2 + ((size_t)e * Ff + n0 + jr + 16) * Dd + c8;
    } else {
        int row = tid >> 1, colb = (tid & 1) * 16;
        b1m = W1 + ((size_t)e * Ff + n0 + row) * Dd + colb;
        b2m = W2 + ((size_t)e * Ff + n0 + row) * Dd + colb;
        sB1w = &sB1[row * 32 + colb];
        sB2w = &sB2[row * 32 + colb];
    }

    const unsigned short* sAr = &sA[(wm * 64 + lane15) * 32 + quad * 8];
    const unsigned short* sB1r = &sB1[(wn * 64 + lane15) * 32 + quad * 8];
    const unsigned short* sB2r = &sB2[(wn * 64 + lane15) * 32 + quad * 8];

    for (int m0 = blockIdx.y * 128; m0 < cnt; m0 += gridDim.y * 128) {
        int r0 = m0 + jr;      if (r0 >= cnt) r0 = cnt - 1;
        int r1 = m0 + jr + 16; if (r1 >= cnt) r1 = cnt - 1;
        const unsigned short* a0 = xb + (size_t)list_tok[bs + r0] * Dd + c8;
        const unsigned short* a1 = xb + (size_t)list_tok[bs + r1] * Dd + c8;

        floatx4 acc1[4][4] = {};
        floatx4 acc2[4][4] = {};

        for (int k0 = 0; k0 < Dd; k0 += 32) {
            gload16(a0 + k0, ldsA0);
            gload16(a1 + k0, ldsA1);
            if constexpr (BF) {
                gload16(b1r0 + k0, ldsB10);
                gload16(b1r1 + k0, ldsB11);
                gload16(b2r0 + k0, ldsB20);
                gload16(b2r1 + k0, ldsB21);
            } else {
                stage16(sB1w, b1m + k0);
                stage16(sB2w, b2m + k0);
            }
            __syncthreads();
            short8 af[4], bf1[4], bf2[4];
#pragma unroll
            for (int i = 0; i < 4; i++) {
                af[i]  = *reinterpret_cast<const short8*>(sAr + i * 16 * 32);
                bf1[i] = *reinterpret_cast<const short8*>(sB1r + i * 16 * 32);
                bf2[i] = *reinterpret_cast<const short8*>(sB2r + i * 16 * 32);
            }
#pragma unroll
            for (int mi = 0; mi < 4; mi++)
#pragma unroll
                for (int ni = 0; ni < 4; ni++) {
                    acc1[mi][ni] = __builtin_amdgcn_mfma_f32_16x16x32_bf16(af[mi], bf1[ni], acc1[mi][ni], 0, 0, 0);
                    acc2[mi][ni] = __builtin_amdgcn_mfma_f32_16x16x32_bf16(af[mi], bf2[ni], acc2[mi][ni], 0, 0, 0);
                }
            __syncthreads();
        }

#pragma unroll
        for (int mi = 0; mi < 4; mi++) {
#pragma unroll
            for (int i = 0; i < 4; i++) {
                int rr = m0 + wm * 64 + mi * 16 + quad * 4 + i;
                if (rr < cnt) {
                    unsigned short* hp = hidden + (size_t)(bs + rr) * Ff + n0 + wn * 64;
#pragma unroll
                    for (int ni = 0; ni < 4; ni++) {
                        float h1 = acc1[mi][ni][i];
                        float h2 = acc2[mi][ni][i];
                        float hv = h1 / (1.f + expf(-h1)) * h2;
                        hp[ni * 16 + lane15] = f2bf(hv);
                    }
                }
            }
        }
    }
}

// ---------------- GEMM2: y[pos] = hidden[pos] W3^T (SCR) or atomic out += p*(...) ----------------
template <typename WT, bool SCR>
__global__ __launch_bounds__(256, 4) void gemm2_kernel(
    const unsigned short* __restrict__ hidden,
    const WT* __restrict__ W3,
    float* __restrict__ outy,
    const int* __restrict__ list_tok, const float* __restrict__ list_prob,
    const int* __restrict__ meta) {
    constexpr bool BF = (sizeof(WT) == 2);
    int e = blockIdx.z;
    int cnt = meta[e];
    int bs = meta[16 + e];
    int n0 = blockIdx.x * 128;

    __shared__ unsigned short sA[128 * 32];
    __shared__ unsigned short sB[128 * 32];

    int tid = threadIdx.x;
    int lane = tid & 63;
    int w = tid >> 6;
    int wm = w >> 1, wn = w & 1;
    int lane15 = lane & 15, quad = lane >> 4;

    int jr = w * 32 + (lane >> 2);
    int c8 = (lane & 3) * 8;
    unsigned short* ldsA0 = sA + w * 1024;
    unsigned short* ldsA1 = sA + w * 1024 + 512;
    unsigned short* ldsB0 = sB + w * 1024;
    unsigned short* ldsB1 = sB + w * 1024 + 512;

    const WT *br0 = nullptr, *br1 = nullptr, *bm = nullptr;
    unsigned short* sBw = nullptr;
    if constexpr (BF) {
        br0 = W3 + ((size_t)e * Dd + n0 + jr) * Ff + c8;
        br1 = W3 + ((size_t)e * Dd + n0 + jr + 16) * Ff + c8;
    } else {
        int row = tid >> 1, colb = (tid & 1) * 16;
        bm = W3 + ((size_t)e * Dd + n0 + row) * Ff + colb;
        sBw = &sB[row * 32 + colb];
    }

    const unsigned short* sAr = &sA[(wm * 64 + lane15) * 32 + quad * 8];
    const unsigned short* sBr = &sB[(wn * 64 + lane15) * 32 + quad * 8];

    for (int m0 = blockIdx.y * 128; m0 < cnt; m0 += gridDim.y * 128) {
        int r0 = m0 + jr;      if (r0 >= cnt) r0 = cnt - 1;
        int r1 = m0 + jr + 16; if (r1 >= cnt) r1 = cnt - 1;
        const unsigned short* a0 = hidden + (size_t)(bs + r0) * Ff + c8;
        const unsigned short* a1 = hidden + (size_t)(bs + r1) * Ff + c8;

        floatx4 acc[4][4] = {};

        for (int k0 = 0; k0 < Ff; k0 += 32) {
            gload16(a0 + k0, ldsA0);
            gload16(a1 + k0, ldsA1);
            if constexpr (BF) {
                gload16(br0 + k0, ldsB0);
                gload16(br1 + k0, ldsB1);
            } else {
                stage16(sBw, bm + k0);
            }
            __syncthreads();
            short8 af[4], bf[4];
#pragma unroll
            for (int i = 0; i < 4; i++) {
                af[i] = *reinterpret_cast<const short8*>(sAr + i * 16 * 32);
                bf[i] = *reinterpret_cast<const short8*>(sBr + i * 16 * 32);
            }
#pragma unroll
            for (int mi = 0; mi < 4; mi++)
#pragma unroll
                for (int ni = 0; ni < 4; ni++)
                    acc[mi][ni] = __builtin_amdgcn_mfma_f32_16x16x32_bf16(af[mi], bf[ni], acc[mi][ni], 0, 0, 0);
            __syncthreads();
        }

#pragma unroll
        for (int mi = 0; mi < 4; mi++) {
#pragma unroll
            for (int i = 0; i < 4; i++) {
                int rr = m0 + wm * 64 + mi * 16 + quad * 4 + i;
                if (rr < cnt) {
                    int pos = bs + rr;
                    if constexpr (SCR) {
                        float* yp = outy + (size_t)pos * Dd + n0 + wn * 64;
#pragma unroll
                        for (int ni = 0; ni < 4; ni++)
                            yp[ni * 16 + lane15] = acc[mi][ni][i];
                    } else {
                        int tok = list_tok[pos];
                        float p = list_prob[pos];
                        float* op = outy + (size_t)tok * Dd + n0 + wn * 64;
#pragma unroll
                        for (int ni = 0; ni < 4; ni++)
                            atomicAdd(&op[ni * 16 + lane15], p * acc[mi][ni][i]);
                    }
                }
            }
        }
    }
}

// ---------------- combine: out[t] = p0*y[pos0] + p1*y[pos1] ----------------
__global__ void combine_kernel(const float* __restrict__ y,
                               const int* __restrict__ pos_of,
                               const float* __restrict__ tok_prob,
                               float* __restrict__ out) {
    int i = blockIdx.x * 256 + threadIdx.x;   // over TOK * Dd/4
    int t = i >> 8;                           // Dd/4 == 256
    int c = i & 255;
    int p0 = pos_of[t * 2], p1 = pos_of[t * 2 + 1];
    float w0 = tok_prob[t * 2], w1 = tok_prob[t * 2 + 1];
    float4 a = reinterpret_cast<const float4*>(y + (size_t)p0 * Dd)[c];
    float4 b = reinterpret_cast<const float4*>(y + (size_t)p1 * Dd)[c];
    float4 o;
    o.x = w0 * a.x + w1 * b.x;
    o.y = w0 * a.y + w1 * b.y;
    o.z = w0 * a.z + w1 * b.z;
    o.w = w0 * a.w + w1 * b.w;
    reinterpret_cast<float4*>(out + (size_t)t * Dd)[c] = o;
}

// ---------------- host launch ----------------
extern "C" void kernel_launch(void* const* d_in, const int* in_sizes, int n_in,
                              void* d_out, int out_size, void* d_ws, size_t ws_size,
                              hipStream_t stream) {
    const float* x  = (const float*)d_in[0];
    const float* Wg = (const float*)d_in[1];
    const float* W1 = (const float*)d_in[2];
    const float* W2 = (const float*)d_in[3];
    const float* W3 = (const float*)d_in[4];
    float* out = (float*)d_out;

    char* ws = (char*)d_ws;
    size_t off = 0;
    auto alloc = [&](size_t bytes) -> char* {
        size_t o = off;
        off += (bytes + 255) & ~(size_t)255;
        return ws + o;
    };

    int* meta = (int*)alloc(64 * sizeof(int));
    int* tok_idx = (int*)alloc((size_t)TOK * 2 * sizeof(int));
    float* tok_prob = (float*)alloc((size_t)TOK * 2 * sizeof(float));
    int* pos_of = (int*)alloc((size_t)TOK * 2 * sizeof(int));
    int* list_tok = (int*)alloc((size_t)PAIRS * sizeof(int));
    float* list_prob = (float*)alloc((size_t)PAIRS * sizeof(float));
    unsigned short* xb = (unsigned short*)alloc((size_t)TOK * Dd * sizeof(unsigned short));
    unsigned short* hidden = (unsigned short*)alloc((size_t)PAIRS * Ff * sizeof(unsigned short));

    size_t ybytes = (size_t)PAIRS * Dd * sizeof(float);
    bool has_y = (ws_size >= off + ybytes + 4096);
    float* y = nullptr;
    if (has_y) y = (float*)alloc(ybytes);

    size_t wbytes = (size_t)Ee * Ff * Dd * sizeof(unsigned short);
    bool has_w = (ws_size >= off + 3 * wbytes + 4096);
    unsigned short *W1b = nullptr, *W2b = nullptr, *W3b = nullptr;
    if (has_w) {
        W1b = (unsigned short*)alloc(wbytes);
        W2b = (unsigned short*)alloc(wbytes);
        W3b = (unsigned short*)alloc(wbytes);
    }

    // zero meta (and out only if we need atomic accumulation into it)
    int n4z = has_y ? 0 : out_size / 4;
    int zgrid = n4z > 0 ? (n4z + 255) / 256 : 1;
    zero_kernel<<<dim3(zgrid), dim3(256), 0, stream>>>(out, n4z, meta);

    gating_kernel<<<dim3(TOK / 4), dim3(256), 0, stream>>>(x, Wg, tok_idx, tok_prob, meta);
    scan_kernel<<<dim3(1), dim3(1), 0, stream>>>(meta);
    scatter_kernel<<<dim3(TOK / 256), dim3(256), 0, stream>>>(tok_idx, tok_prob, meta,
                                                              list_tok, list_prob, pos_of);

    int xn4 = TOK * Dd / 4;
    cvt_kernel<<<dim3((xn4 + 255) / 256), dim3(256), 0, stream>>>(x, xb, xn4);

    if (has_w) {
        int wn4 = Ee * Ff * Dd / 4;
        cvt_kernel<<<dim3((wn4 + 255) / 256), dim3(256), 0, stream>>>(W1, W1b, wn4);
        cvt_kernel<<<dim3((wn4 + 255) / 256), dim3(256), 0, stream>>>(W2, W2b, wn4);
        cvt_kernel<<<dim3((wn4 + 255) / 256), dim3(256), 0, stream>>>(W3, W3b, wn4);
        gemm1_kernel<unsigned short><<<dim3(Ff / 128, 8, Ee), dim3(256), 0, stream>>>(
            xb, W1b, W2b, hidden, list_tok, meta);
        if (has_y)
            gemm2_kernel<unsigned short, true><<<dim3(Dd / 128, 8, Ee), dim3(256), 0, stream>>>(
                hidden, W3b, y, list_tok, list_prob, meta);
        else
            gemm2_kernel<unsigned short, false><<<dim3(Dd / 128, 8, Ee), dim3(256), 0, stream>>>(
                hidden, W3b, out, list_tok, list_prob, meta);
    } else {
        gemm1_kernel<float><<<dim3(Ff / 128, 8, Ee), dim3(256), 0, stream>>>(
            xb, W1, W2, hidden, list_tok, meta);
        if (has_y)
            gemm2_kernel<float, true><<<dim3(Dd / 128, 8, Ee), dim3(256), 0, stream>>>(
                hidden, W3, y, list_tok, list_prob, meta);
        else
            gemm2_kernel<float, false><<<dim3(Dd / 128, 8, Ee), dim3(256), 0, stream>>>(
                hidden, W3, out, list_tok, list_prob, meta);
    }

    if (has_y)
        combine_kernel<<<dim3(TOK * Dd / 4 / 256), dim3(256), 0, stream>>>(y, pos_of, tok_prob, out);
}

// Round 3
// 665.738 us; speedup vs baseline: 2.1935x; 2.1935x over previous
//
#include <hip/hip_runtime.h>
#include <hip/hip_bf16.h>
#include <cstdint>

// MoE feed-forward, routed top-2 of 8 experts.
// B=2 S=2048 D=1024 F=2048 E=8 K=2.
// R3: fix R2 regression. (1) ws layout shrunk to ~136 MB (y overlays W1b) so the
//     bf16-weight path always engages; (2) __launch_bounds__(256) only — the
//     (256,4) bound squeezed VGPRs to 64 and caused GB-scale scratch spills;
//     (3) keep async global_load_lds staging, grid-stride m-loop, y+combine.

#define Dd 1024
#define Ff 2048
#define Ee 8
#define TOK 4096
#define PAIRS 8192

typedef __attribute__((ext_vector_type(8))) short short8;
typedef __attribute__((ext_vector_type(4))) float floatx4;

__device__ __forceinline__ unsigned short f2bf(float f) {
    unsigned int u = __float_as_uint(f);
    unsigned int r = (u + 0x7FFFu + ((u >> 16) & 1u)) >> 16;
    return (unsigned short)r;
}

// async 16B/lane global->LDS. lds ptr is wave-uniform; lane i lands at lds + i*16B.
__device__ __forceinline__ void gload16(const unsigned short* g, unsigned short* l) {
    __builtin_amdgcn_global_load_lds(
        (const __attribute__((address_space(1))) unsigned int*)g,
        (__attribute__((address_space(3))) unsigned int*)l,
        16, 0, 0);
}

// ---------------- zero meta (+ optionally out) ----------------
__global__ void zero_kernel(float* __restrict__ out, int n4, int* __restrict__ meta) {
    int i = blockIdx.x * blockDim.x + threadIdx.x;
    if (i < n4) reinterpret_cast<float4*>(out)[i] = make_float4(0.f, 0.f, 0.f, 0.f);
    if (i < 32) meta[i] = 0;   // meta: [0..7]=counts [8..15]=cursor [16..23]=base
}

// ---------------- gating: fp32 scores, top-2, softmax ----------------
__global__ void gating_kernel(const float* __restrict__ x, const float* __restrict__ Wg,
                              int* __restrict__ tok_idx, float* __restrict__ tok_prob,
                              int* __restrict__ meta) {
    int lane = threadIdx.x & 63;
    int w = threadIdx.x >> 6;
    int t = blockIdx.x * 4 + w;

    float xr[16];
    const float* xp = x + (size_t)t * Dd;
#pragma unroll
    for (int i = 0; i < 16; i++) xr[i] = xp[lane + i * 64];

    float sc[Ee];
    for (int e = 0; e < Ee; e++) {
        const float* wp = Wg + (size_t)e * Dd;
        float p = 0.f;
#pragma unroll
        for (int i = 0; i < 16; i++) p += xr[i] * wp[lane + i * 64];
        for (int off = 32; off > 0; off >>= 1) p += __shfl_xor(p, off);
        sc[e] = p;
    }
    if (lane == 0) {
        int e1 = 0, e2 = 0;
        float b1 = -1e30f, b2 = -1e30f;
        for (int e = 0; e < Ee; e++) {
            float s = sc[e];
            if (s > b1) { b2 = b1; e2 = e1; b1 = s; e1 = e; }
            else if (s > b2) { b2 = s; e2 = e; }
        }
        float p1 = 1.f / (1.f + expf(b2 - b1));
        float p2 = 1.f - p1;
        tok_idx[t * 2 + 0] = e1;
        tok_idx[t * 2 + 1] = e2;
        tok_prob[t * 2 + 0] = p1;
        tok_prob[t * 2 + 1] = p2;
        atomicAdd(&meta[e1], 1);
        atomicAdd(&meta[e2], 1);
    }
}

// ---------------- exclusive scan of counts -> base ----------------
__global__ void scan_kernel(int* __restrict__ meta) {
    int b = 0;
    for (int e = 0; e < Ee; e++) { meta[16 + e] = b; b += meta[e]; }
}

// ---------------- scatter tokens into per-expert lists (+ inverse map) ----------------
__global__ void scatter_kernel(const int* __restrict__ tok_idx, const float* __restrict__ tok_prob,
                               int* __restrict__ meta,
                               int* __restrict__ list_tok, float* __restrict__ list_prob,
                               int* __restrict__ pos_of) {
    int t = blockIdx.x * blockDim.x + threadIdx.x;
    if (t >= TOK) return;
    for (int k = 0; k < 2; k++) {
        int e = tok_idx[t * 2 + k];
        int pos = meta[16 + e] + atomicAdd(&meta[8 + e], 1);
        list_tok[pos] = t;
        list_prob[pos] = tok_prob[t * 2 + k];
        pos_of[t * 2 + k] = pos;
    }
}

// ---------------- fp32 -> bf16 convert ----------------
__global__ void cvt_kernel(const float* __restrict__ src, unsigned short* __restrict__ dst, int n4) {
    int i = blockIdx.x * blockDim.x + threadIdx.x;
    if (i >= n4) return;
    float4 v = reinterpret_cast<const float4*>(src)[i];
    uint2 o;
    o.x = (unsigned)f2bf(v.x) | ((unsigned)f2bf(v.y) << 16);
    o.y = (unsigned)f2bf(v.z) | ((unsigned)f2bf(v.w) << 16);
    reinterpret_cast<uint2*>(dst)[i] = o;
}

// ---------------- manual fp32->bf16 LDS staging (fallback path only) ----------------
__device__ __forceinline__ void stage16(unsigned short* dst, const float* src) {
    const float4* s = reinterpret_cast<const float4*>(src);
    float4 v0 = s[0], v1 = s[1], v2 = s[2], v3 = s[3];
    uint4 o0, o1;
    o0.x = (unsigned)f2bf(v0.x) | ((unsigned)f2bf(v0.y) << 16);
    o0.y = (unsigned)f2bf(v0.z) | ((unsigned)f2bf(v0.w) << 16);
    o0.z = (unsigned)f2bf(v1.x) | ((unsigned)f2bf(v1.y) << 16);
    o0.w = (unsigned)f2bf(v1.z) | ((unsigned)f2bf(v1.w) << 16);
    o1.x = (unsigned)f2bf(v2.x) | ((unsigned)f2bf(v2.y) << 16);
    o1.y = (unsigned)f2bf(v2.z) | ((unsigned)f2bf(v2.w) << 16);
    o1.z = (unsigned)f2bf(v3.x) | ((unsigned)f2bf(v3.y) << 16);
    o1.w = (unsigned)f2bf(v3.z) | ((unsigned)f2bf(v3.w) << 16);
    uint4* d = reinterpret_cast<uint4*>(dst);
    d[0] = o0;
    d[1] = o1;
}

// ---------------- GEMM1: hidden = silu(x W1^T) * (x W2^T), routed ----------------
template <typename WT>
__global__ __launch_bounds__(256) void gemm1_kernel(
    const unsigned short* __restrict__ xb,
    const WT* __restrict__ W1, const WT* __restrict__ W2,
    unsigned short* __restrict__ hidden,
    const int* __restrict__ list_tok, const int* __restrict__ meta) {
    constexpr bool BF = (sizeof(WT) == 2);
    int e = blockIdx.z;
    int cnt = meta[e];
    int bs = meta[16 + e];
    int n0 = blockIdx.x * 128;

    __shared__ unsigned short sA[128 * 32];
    __shared__ unsigned short sB1[128 * 32];
    __shared__ unsigned short sB2[128 * 32];

    int tid = threadIdx.x;
    int lane = tid & 63;
    int w = tid >> 6;
    int wm = w >> 1, wn = w & 1;
    int lane15 = lane & 15, quad = lane >> 4;

    // async staging geometry: issue j of wave w covers rows [w*32+j*16, +16)
    int jr = w * 32 + (lane >> 2);   // row for issue 0 (+16 for issue 1)
    int c8 = (lane & 3) * 8;         // ushort offset of this lane's 16B chunk
    unsigned short* ldsA0 = sA + w * 1024;
    unsigned short* ldsA1 = sA + w * 1024 + 512;
    unsigned short* ldsB10 = sB1 + w * 1024;
    unsigned short* ldsB11 = sB1 + w * 1024 + 512;
    unsigned short* ldsB20 = sB2 + w * 1024;
    unsigned short* ldsB21 = sB2 + w * 1024 + 512;

    const WT *b1r0 = nullptr, *b1r1 = nullptr, *b2r0 = nullptr, *b2r1 = nullptr;
    const WT *b1m = nullptr, *b2m = nullptr;
    unsigned short *sB1w = nullptr, *sB2w = nullptr;
    if constexpr (BF) {
        b1r0 = W1 + ((size_t)e * Ff + n0 + jr) * Dd + c8;
        b1r1 = W1 + ((size_t)e * Ff + n0 + jr + 16) * Dd + c8;
        b2r0 = W2 + ((size_t)e * Ff + n0 + jr) * Dd + c8;
        b2r1 = W2 + ((size_t)e * Ff + n0 + jr + 16) * Dd + c8;
    } else {
        int row = tid >> 1, colb = (tid & 1) * 16;
        b1m = W1 + ((size_t)e * Ff + n0 + row) * Dd + colb;
        b2m = W2 + ((size_t)e * Ff + n0 + row) * Dd + colb;
        sB1w = &sB1[row * 32 + colb];
        sB2w = &sB2[row * 32 + colb];
    }

    const unsigned short* sAr = &sA[(wm * 64 + lane15) * 32 + quad * 8];
    const unsigned short* sB1r = &sB1[(wn * 64 + lane15) * 32 + quad * 8];
    const unsigned short* sB2r = &sB2[(wn * 64 + lane15) * 32 + quad * 8];

    for (int m0 = blockIdx.y * 128; m0 < cnt; m0 += gridDim.y * 128) {
        int r0 = m0 + jr;      if (r0 >= cnt) r0 = cnt - 1;
        int r1 = m0 + jr + 16; if (r1 >= cnt) r1 = cnt - 1;
        const unsigned short* a0 = xb + (size_t)list_tok[bs + r0] * Dd + c8;
        const unsigned short* a1 = xb + (size_t)list_tok[bs + r1] * Dd + c8;

        floatx4 acc1[4][4] = {};
        floatx4 acc2[4][4] = {};

        for (int k0 = 0; k0 < Dd; k0 += 32) {
            gload16(a0 + k0, ldsA0);
            gload16(a1 + k0, ldsA1);
            if constexpr (BF) {
                gload16(b1r0 + k0, ldsB10);
                gload16(b1r1 + k0, ldsB11);
                gload16(b2r0 + k0, ldsB20);
                gload16(b2r1 + k0, ldsB21);
            } else {
                stage16(sB1w, b1m + k0);
                stage16(sB2w, b2m + k0);
            }
            __syncthreads();
            short8 af[4], bf1[4], bf2[4];
#pragma unroll
            for (int i = 0; i < 4; i++) {
                af[i]  = *reinterpret_cast<const short8*>(sAr + i * 16 * 32);
                bf1[i] = *reinterpret_cast<const short8*>(sB1r + i * 16 * 32);
                bf2[i] = *reinterpret_cast<const short8*>(sB2r + i * 16 * 32);
            }
#pragma unroll
            for (int mi = 0; mi < 4; mi++)
#pragma unroll
                for (int ni = 0; ni < 4; ni++) {
                    acc1[mi][ni] = __builtin_amdgcn_mfma_f32_16x16x32_bf16(af[mi], bf1[ni], acc1[mi][ni], 0, 0, 0);
                    acc2[mi][ni] = __builtin_amdgcn_mfma_f32_16x16x32_bf16(af[mi], bf2[ni], acc2[mi][ni], 0, 0, 0);
                }
            __syncthreads();
        }

#pragma unroll
        for (int mi = 0; mi < 4; mi++) {
#pragma unroll
            for (int i = 0; i < 4; i++) {
                int rr = m0 + wm * 64 + mi * 16 + quad * 4 + i;
                if (rr < cnt) {
                    unsigned short* hp = hidden + (size_t)(bs + rr) * Ff + n0 + wn * 64;
#pragma unroll
                    for (int ni = 0; ni < 4; ni++) {
                        float h1 = acc1[mi][ni][i];
                        float h2 = acc2[mi][ni][i];
                        float hv = h1 / (1.f + expf(-h1)) * h2;
                        hp[ni * 16 + lane15] = f2bf(hv);
                    }
                }
            }
        }
    }
}

// ---------------- GEMM2: y[pos] = hidden[pos] W3^T (SCR) or atomic out += p*(...) ----------------
template <typename WT, bool SCR>
__global__ __launch_bounds__(256) void gemm2_kernel(
    const unsigned short* __restrict__ hidden,
    const WT* __restrict__ W3,
    float* __restrict__ outy,
    const int* __restrict__ list_tok, const float* __restrict__ list_prob,
    const int* __restrict__ meta) {
    constexpr bool BF = (sizeof(WT) == 2);
    int e = blockIdx.z;
    int cnt = meta[e];
    int bs = meta[16 + e];
    int n0 = blockIdx.x * 128;

    __shared__ unsigned short sA[128 * 32];
    __shared__ unsigned short sB[128 * 32];

    int tid = threadIdx.x;
    int lane = tid & 63;
    int w = tid >> 6;
    int wm = w >> 1, wn = w & 1;
    int lane15 = lane & 15, quad = lane >> 4;

    int jr = w * 32 + (lane >> 2);
    int c8 = (lane & 3) * 8;
    unsigned short* ldsA0 = sA + w * 1024;
    unsigned short* ldsA1 = sA + w * 1024 + 512;
    unsigned short* ldsB0 = sB + w * 1024;
    unsigned short* ldsB1 = sB + w * 1024 + 512;

    const WT *br0 = nullptr, *br1 = nullptr, *bm = nullptr;
    unsigned short* sBw = nullptr;
    if constexpr (BF) {
        br0 = W3 + ((size_t)e * Dd + n0 + jr) * Ff + c8;
        br1 = W3 + ((size_t)e * Dd + n0 + jr + 16) * Ff + c8;
    } else {
        int row = tid >> 1, colb = (tid & 1) * 16;
        bm = W3 + ((size_t)e * Dd + n0 + row) * Ff + colb;
        sBw = &sB[row * 32 + colb];
    }

    const unsigned short* sAr = &sA[(wm * 64 + lane15) * 32 + quad * 8];
    const unsigned short* sBr = &sB[(wn * 64 + lane15) * 32 + quad * 8];

    for (int m0 = blockIdx.y * 128; m0 < cnt; m0 += gridDim.y * 128) {
        int r0 = m0 + jr;      if (r0 >= cnt) r0 = cnt - 1;
        int r1 = m0 + jr + 16; if (r1 >= cnt) r1 = cnt - 1;
        const unsigned short* a0 = hidden + (size_t)(bs + r0) * Ff + c8;
        const unsigned short* a1 = hidden + (size_t)(bs + r1) * Ff + c8;

        floatx4 acc[4][4] = {};

        for (int k0 = 0; k0 < Ff; k0 += 32) {
            gload16(a0 + k0, ldsA0);
            gload16(a1 + k0, ldsA1);
            if constexpr (BF) {
                gload16(br0 + k0, ldsB0);
                gload16(br1 + k0, ldsB1);
            } else {
                stage16(sBw, bm + k0);
            }
            __syncthreads();
            short8 af[4], bf[4];
#pragma unroll
            for (int i = 0; i < 4; i++) {
                af[i] = *reinterpret_cast<const short8*>(sAr + i * 16 * 32);
                bf[i] = *reinterpret_cast<const short8*>(sBr + i * 16 * 32);
            }
#pragma unroll
            for (int mi = 0; mi < 4; mi++)
#pragma unroll
                for (int ni = 0; ni < 4; ni++)
                    acc[mi][ni] = __builtin_amdgcn_mfma_f32_16x16x32_bf16(af[mi], bf[ni], acc[mi][ni], 0, 0, 0);
            __syncthreads();
        }

#pragma unroll
        for (int mi = 0; mi < 4; mi++) {
#pragma unroll
            for (int i = 0; i < 4; i++) {
                int rr = m0 + wm * 64 + mi * 16 + quad * 4 + i;
                if (rr < cnt) {
                    int pos = bs + rr;
                    if constexpr (SCR) {
                        float* yp = outy + (size_t)pos * Dd + n0 + wn * 64;
#pragma unroll
                        for (int ni = 0; ni < 4; ni++)
                            yp[ni * 16 + lane15] = acc[mi][ni][i];
                    } else {
                        int tok = list_tok[pos];
                        float p = list_prob[pos];
                        float* op = outy + (size_t)tok * Dd + n0 + wn * 64;
#pragma unroll
                        for (int ni = 0; ni < 4; ni++)
                            atomicAdd(&op[ni * 16 + lane15], p * acc[mi][ni][i]);
                    }
                }
            }
        }
    }
}

// ---------------- combine: out[t] = p0*y[pos0] + p1*y[pos1] ----------------
__global__ void combine_kernel(const float* __restrict__ y,
                               const int* __restrict__ pos_of,
                               const float* __restrict__ tok_prob,
                               float* __restrict__ out) {
    int i = blockIdx.x * 256 + threadIdx.x;   // over TOK * Dd/4
    int t = i >> 8;                           // Dd/4 == 256
    int c = i & 255;
    int p0 = pos_of[t * 2], p1 = pos_of[t * 2 + 1];
    float w0 = tok_prob[t * 2], w1 = tok_prob[t * 2 + 1];
    float4 a = reinterpret_cast<const float4*>(y + (size_t)p0 * Dd)[c];
    float4 b = reinterpret_cast<const float4*>(y + (size_t)p1 * Dd)[c];
    float4 o;
    o.x = w0 * a.x + w1 * b.x;
    o.y = w0 * a.y + w1 * b.y;
    o.z = w0 * a.z + w1 * b.z;
    o.w = w0 * a.w + w1 * b.w;
    reinterpret_cast<float4*>(out + (size_t)t * Dd)[c] = o;
}

// ---------------- host launch ----------------
extern "C" void kernel_launch(void* const* d_in, const int* in_sizes, int n_in,
                              void* d_out, int out_size, void* d_ws, size_t ws_size,
                              hipStream_t stream) {
    const float* x  = (const float*)d_in[0];
    const float* Wg = (const float*)d_in[1];
    const float* W1 = (const float*)d_in[2];
    const float* W2 = (const float*)d_in[3];
    const float* W3 = (const float*)d_in[4];
    float* out = (float*)d_out;

    char* ws = (char*)d_ws;
    size_t off = 0;
    auto alloc = [&](size_t bytes) -> char* {
        size_t o = off;
        off += (bytes + 255) & ~(size_t)255;
        return ws + o;
    };

    int* meta = (int*)alloc(64 * sizeof(int));
    int* tok_idx = (int*)alloc((size_t)TOK * 2 * sizeof(int));
    float* tok_prob = (float*)alloc((size_t)TOK * 2 * sizeof(float));
    int* pos_of = (int*)alloc((size_t)TOK * 2 * sizeof(int));
    int* list_tok = (int*)alloc((size_t)PAIRS * sizeof(int));
    float* list_prob = (float*)alloc((size_t)PAIRS * sizeof(float));
    unsigned short* xb = (unsigned short*)alloc((size_t)TOK * Dd * sizeof(unsigned short));
    unsigned short* hidden = (unsigned short*)alloc((size_t)PAIRS * Ff * sizeof(unsigned short));

    // bf16 weight copies; y (32 MB fp32) OVERLAYS W1b (32 MB bf16):
    // W1b is only read during gemm1; y is only written during gemm2/combine,
    // which are stream-ordered after gemm1. Total ws need ≈ 136 MB.
    size_t wbytes = (size_t)Ee * Ff * Dd * sizeof(unsigned short);
    size_t ybytes = (size_t)PAIRS * Dd * sizeof(float);  // == wbytes == 32 MB
    bool has_w = (ws_size >= off + 3 * wbytes + 4096);
    unsigned short *W1b = nullptr, *W2b = nullptr, *W3b = nullptr;
    float* y = nullptr;
    bool has_y = false;
    if (has_w) {
        W1b = (unsigned short*)alloc(wbytes);
        W2b = (unsigned short*)alloc(wbytes);
        W3b = (unsigned short*)alloc(wbytes);
        y = (float*)W1b;           // overlay
        has_y = true;
    } else if (ws_size >= off + ybytes + 4096) {
        y = (float*)alloc(ybytes);
        has_y = true;
    }

    // zero meta (and out only if we need atomic accumulation into it)
    int n4z = has_y ? 0 : out_size / 4;
    int zgrid = n4z > 0 ? (n4z + 255) / 256 : 1;
    zero_kernel<<<dim3(zgrid), dim3(256), 0, stream>>>(out, n4z, meta);

    gating_kernel<<<dim3(TOK / 4), dim3(256), 0, stream>>>(x, Wg, tok_idx, tok_prob, meta);
    scan_kernel<<<dim3(1), dim3(1), 0, stream>>>(meta);
    scatter_kernel<<<dim3(TOK / 256), dim3(256), 0, stream>>>(tok_idx, tok_prob, meta,
                                                              list_tok, list_prob, pos_of);

    int xn4 = TOK * Dd / 4;
    cvt_kernel<<<dim3((xn4 + 255) / 256), dim3(256), 0, stream>>>(x, xb, xn4);

    if (has_w) {
        int wn4 = Ee * Ff * Dd / 4;
        cvt_kernel<<<dim3((wn4 + 255) / 256), dim3(256), 0, stream>>>(W1, W1b, wn4);
        cvt_kernel<<<dim3((wn4 + 255) / 256), dim3(256), 0, stream>>>(W2, W2b, wn4);
        cvt_kernel<<<dim3((wn4 + 255) / 256), dim3(256), 0, stream>>>(W3, W3b, wn4);
        gemm1_kernel<unsigned short><<<dim3(Ff / 128, 8, Ee), dim3(256), 0, stream>>>(
            xb, W1b, W2b, hidden, list_tok, meta);
        gemm2_kernel<unsigned short, true><<<dim3(Dd / 128, 8, Ee), dim3(256), 0, stream>>>(
            hidden, W3b, y, list_tok, list_prob, meta);
    } else {
        gemm1_kernel<float><<<dim3(Ff / 128, 8, Ee), dim3(256), 0, stream>>>(
            xb, W1, W2, hidden, list_tok, meta);
        if (has_y)
            gemm2_kernel<float, true><<<dim3(Dd / 128, 8, Ee), dim3(256), 0, stream>>>(
                hidden, W3, y, list_tok, list_prob, meta);
        else
            gemm2_kernel<float, false><<<dim3(Dd / 128, 8, Ee), dim3(256), 0, stream>>>(
                hidden, W3, out, list_tok, list_prob, meta);
    }

    if (has_y)
        combine_kernel<<<dim3(TOK * Dd / 4 / 256), dim3(256), 0, stream>>>(y, pos_of, tok_prob, out);
}

// Round 4
// 595.465 us; speedup vs baseline: 2.4524x; 1.1180x over previous
//
#include <hip/hip_runtime.h>
#include <hip/hip_bf16.h>
#include <cstdint>

// MoE feed-forward, routed top-2 of 8 experts.
// B=2 S=2048 D=1024 F=2048 E=8 K=2.
// R4: fix R3 register-pressure regression (VGPR 212 -> 2 waves/SIMD).
//   - gemm1 split into two single-accumulator m97-shape kernels:
//       gemm1a: h1 = x W1^T          (bf16 scratch)
//       gemm1b: hidden = silu(h1) * (x W2^T)
//   - no grid-stride m-loop: early-exit blocks, grid y=32 (worst-case cnt)
//   - async global_load_lds staging kept (m97 pattern), plain launch_bounds(256)

#define Dd 1024
#define Ff 2048
#define Ee 8
#define TOK 4096
#define PAIRS 8192

typedef __attribute__((ext_vector_type(8))) short short8;
typedef __attribute__((ext_vector_type(4))) float floatx4;

__device__ __forceinline__ unsigned short f2bf(float f) {
    unsigned int u = __float_as_uint(f);
    unsigned int r = (u + 0x7FFFu + ((u >> 16) & 1u)) >> 16;
    return (unsigned short)r;
}
__device__ __forceinline__ float bf2f(unsigned short u) {
    return __uint_as_float(((unsigned)u) << 16);
}

// async 16B/lane global->LDS. lds ptr is wave-uniform; lane i lands at lds + i*16B.
__device__ __forceinline__ void gload16(const unsigned short* g, unsigned short* l) {
    __builtin_amdgcn_global_load_lds(
        (const __attribute__((address_space(1))) unsigned int*)g,
        (__attribute__((address_space(3))) unsigned int*)l,
        16, 0, 0);
}

// ---------------- zero meta (+ optionally out) ----------------
__global__ void zero_kernel(float* __restrict__ out, int n4, int* __restrict__ meta) {
    int i = blockIdx.x * blockDim.x + threadIdx.x;
    if (i < n4) reinterpret_cast<float4*>(out)[i] = make_float4(0.f, 0.f, 0.f, 0.f);
    if (i < 32) meta[i] = 0;   // meta: [0..7]=counts [8..15]=cursor [16..23]=base
}

// ---------------- gating: fp32 scores, top-2, softmax ----------------
__global__ void gating_kernel(const float* __restrict__ x, const float* __restrict__ Wg,
                              int* __restrict__ tok_idx, float* __restrict__ tok_prob,
                              int* __restrict__ meta) {
    int lane = threadIdx.x & 63;
    int w = threadIdx.x >> 6;
    int t = blockIdx.x * 4 + w;

    float xr[16];
    const float* xp = x + (size_t)t * Dd;
#pragma unroll
    for (int i = 0; i < 16; i++) xr[i] = xp[lane + i * 64];

    float sc[Ee];
    for (int e = 0; e < Ee; e++) {
        const float* wp = Wg + (size_t)e * Dd;
        float p = 0.f;
#pragma unroll
        for (int i = 0; i < 16; i++) p += xr[i] * wp[lane + i * 64];
        for (int off = 32; off > 0; off >>= 1) p += __shfl_xor(p, off);
        sc[e] = p;
    }
    if (lane == 0) {
        int e1 = 0, e2 = 0;
        float b1 = -1e30f, b2 = -1e30f;
        for (int e = 0; e < Ee; e++) {
            float s = sc[e];
            if (s > b1) { b2 = b1; e2 = e1; b1 = s; e1 = e; }
            else if (s > b2) { b2 = s; e2 = e; }
        }
        float p1 = 1.f / (1.f + expf(b2 - b1));
        float p2 = 1.f - p1;
        tok_idx[t * 2 + 0] = e1;
        tok_idx[t * 2 + 1] = e2;
        tok_prob[t * 2 + 0] = p1;
        tok_prob[t * 2 + 1] = p2;
        atomicAdd(&meta[e1], 1);
        atomicAdd(&meta[e2], 1);
    }
}

// ---------------- exclusive scan of counts -> base ----------------
__global__ void scan_kernel(int* __restrict__ meta) {
    int b = 0;
    for (int e = 0; e < Ee; e++) { meta[16 + e] = b; b += meta[e]; }
}

// ---------------- scatter tokens into per-expert lists (+ inverse map) ----------------
__global__ void scatter_kernel(const int* __restrict__ tok_idx, const float* __restrict__ tok_prob,
                               int* __restrict__ meta,
                               int* __restrict__ list_tok, float* __restrict__ list_prob,
                               int* __restrict__ pos_of) {
    int t = blockIdx.x * blockDim.x + threadIdx.x;
    if (t >= TOK) return;
    for (int k = 0; k < 2; k++) {
        int e = tok_idx[t * 2 + k];
        int pos = meta[16 + e] + atomicAdd(&meta[8 + e], 1);
        list_tok[pos] = t;
        list_prob[pos] = tok_prob[t * 2 + k];
        pos_of[t * 2 + k] = pos;
    }
}

// ---------------- fp32 -> bf16 convert ----------------
__global__ void cvt_kernel(const float* __restrict__ src, unsigned short* __restrict__ dst, int n4) {
    int i = blockIdx.x * blockDim.x + threadIdx.x;
    if (i >= n4) return;
    float4 v = reinterpret_cast<const float4*>(src)[i];
    uint2 o;
    o.x = (unsigned)f2bf(v.x) | ((unsigned)f2bf(v.y) << 16);
    o.y = (unsigned)f2bf(v.z) | ((unsigned)f2bf(v.w) << 16);
    reinterpret_cast<uint2*>(dst)[i] = o;
}

// ---------------- manual fp32->bf16 LDS staging (fallback path only) ----------------
__device__ __forceinline__ void stage16(unsigned short* dst, const float* src) {
    const float4* s = reinterpret_cast<const float4*>(src);
    float4 v0 = s[0], v1 = s[1], v2 = s[2], v3 = s[3];
    uint4 o0, o1;
    o0.x = (unsigned)f2bf(v0.x) | ((unsigned)f2bf(v0.y) << 16);
    o0.y = (unsigned)f2bf(v0.z) | ((unsigned)f2bf(v0.w) << 16);
    o0.z = (unsigned)f2bf(v1.x) | ((unsigned)f2bf(v1.y) << 16);
    o0.w = (unsigned)f2bf(v1.z) | ((unsigned)f2bf(v1.w) << 16);
    o1.x = (unsigned)f2bf(v2.x) | ((unsigned)f2bf(v2.y) << 16);
    o1.y = (unsigned)f2bf(v2.z) | ((unsigned)f2bf(v2.w) << 16);
    o1.z = (unsigned)f2bf(v3.x) | ((unsigned)f2bf(v3.y) << 16);
    o1.w = (unsigned)f2bf(v3.z) | ((unsigned)f2bf(v3.w) << 16);
    uint4* d = reinterpret_cast<uint4*>(dst);
    d[0] = o0;
    d[1] = o1;
}

// ============ routed single-acc GEMM kernels (m97 shape) ============
// EPI: 0 = store bf16 C to h1raw
//      1 = read h1raw, hidden = silu(h1)*C (bf16)
//      2 = store fp32 C to y[pos]
template <typename WT, int EPI>
__global__ __launch_bounds__(256) void rgemm_kernel(
    const unsigned short* __restrict__ A,      // row source (xb or hidden), stride AK
    const WT* __restrict__ Bw,                 // weights, rows of length AK
    unsigned short* __restrict__ h1raw,        // EPI 0 write / EPI 1 read
    unsigned short* __restrict__ hout,         // EPI 1 write
    float* __restrict__ y,                     // EPI 2 write
    const int* __restrict__ list_tok, const int* __restrict__ meta,
    int AK, int BN, int arow_is_list) {
    constexpr bool BF = (sizeof(WT) == 2);
    int e = blockIdx.z;
    int cnt = meta[e];
    int m0 = blockIdx.y * 128;
    if (m0 >= cnt) return;
    int bs = meta[16 + e];
    int n0 = blockIdx.x * 128;

    __shared__ unsigned short sA[128 * 32];
    __shared__ unsigned short sB[128 * 32];

    int tid = threadIdx.x;
    int lane = tid & 63, w = tid >> 6;
    int wm = w >> 1, wn = w & 1;
    int lane15 = lane & 15, quad = lane >> 4;

    // async staging geometry: wave w stages rows [w*32, w*32+16) then +16
    int jr = w * 32 + (lane >> 2);
    int c8 = (lane & 3) * 8;
    unsigned short* ldsA0 = sA + w * 1024;
    unsigned short* ldsA1 = ldsA0 + 512;
    unsigned short* ldsB0 = sB + w * 1024;
    unsigned short* ldsB1 = ldsB0 + 512;

    int r0 = m0 + jr;      if (r0 >= cnt) r0 = cnt - 1;
    int r1 = m0 + jr + 16; if (r1 >= cnt) r1 = cnt - 1;
    size_t ar0 = arow_is_list ? (size_t)list_tok[bs + r0] : (size_t)(bs + r0);
    size_t ar1 = arow_is_list ? (size_t)list_tok[bs + r1] : (size_t)(bs + r1);
    const unsigned short* a0 = A + ar0 * AK + c8;
    const unsigned short* a1 = A + ar1 * AK + c8;

    const WT *b0 = nullptr, *b1 = nullptr, *bmp = nullptr;
    unsigned short* sBw = nullptr;
    if constexpr (BF) {
        b0 = Bw + ((size_t)e * BN + n0 + jr) * AK + c8;
        b1 = Bw + ((size_t)e * BN + n0 + jr + 16) * AK + c8;
    } else {
        int row = tid >> 1, colb = (tid & 1) * 16;
        bmp = Bw + ((size_t)e * BN + n0 + row) * AK + colb;
        sBw = &sB[row * 32 + colb];
    }

    const unsigned short* sAr = &sA[(wm * 64 + lane15) * 32 + quad * 8];
    const unsigned short* sBr = &sB[(wn * 64 + lane15) * 32 + quad * 8];

    floatx4 acc[4][4] = {};

    for (int k0 = 0; k0 < AK; k0 += 32) {
        gload16(a0 + k0, ldsA0);
        gload16(a1 + k0, ldsA1);
        if constexpr (BF) {
            gload16(b0 + k0, ldsB0);
            gload16(b1 + k0, ldsB1);
        } else {
            stage16(sBw, bmp + k0);
        }
        __syncthreads();
        short8 af[4], bfr[4];
#pragma unroll
        for (int i = 0; i < 4; i++) {
            af[i]  = *reinterpret_cast<const short8*>(sAr + i * 16 * 32);
            bfr[i] = *reinterpret_cast<const short8*>(sBr + i * 16 * 32);
        }
#pragma unroll
        for (int mi = 0; mi < 4; mi++)
#pragma unroll
            for (int ni = 0; ni < 4; ni++)
                acc[mi][ni] = __builtin_amdgcn_mfma_f32_16x16x32_bf16(af[mi], bfr[ni], acc[mi][ni], 0, 0, 0);
        __syncthreads();
    }

#pragma unroll
    for (int mi = 0; mi < 4; mi++) {
#pragma unroll
        for (int i = 0; i < 4; i++) {
            int rr = m0 + wm * 64 + mi * 16 + quad * 4 + i;
            if (rr < cnt) {
                int pos = bs + rr;
                if constexpr (EPI == 0) {
                    unsigned short* hp = h1raw + (size_t)pos * BN + n0 + wn * 64;
#pragma unroll
                    for (int ni = 0; ni < 4; ni++)
                        hp[ni * 16 + lane15] = f2bf(acc[mi][ni][i]);
                } else if constexpr (EPI == 1) {
                    const unsigned short* h1p = h1raw + (size_t)pos * BN + n0 + wn * 64;
                    unsigned short* hp = hout + (size_t)pos * BN + n0 + wn * 64;
#pragma unroll
                    for (int ni = 0; ni < 4; ni++) {
                        float h1 = bf2f(h1p[ni * 16 + lane15]);
                        float h2 = acc[mi][ni][i];
                        float hv = h1 / (1.f + expf(-h1)) * h2;
                        hp[ni * 16 + lane15] = f2bf(hv);
                    }
                } else {
                    float* yp = y + (size_t)pos * BN + n0 + wn * 64;
#pragma unroll
                    for (int ni = 0; ni < 4; ni++)
                        yp[ni * 16 + lane15] = acc[mi][ni][i];
                }
            }
        }
    }
}

// ---------------- combine: out[t] = p0*y[pos0] + p1*y[pos1] ----------------
__global__ void combine_kernel(const float* __restrict__ y,
                               const int* __restrict__ pos_of,
                               const float* __restrict__ tok_prob,
                               float* __restrict__ out) {
    int i = blockIdx.x * 256 + threadIdx.x;   // over TOK * Dd/4
    int t = i >> 8;                           // Dd/4 == 256
    int c = i & 255;
    int p0 = pos_of[t * 2], p1 = pos_of[t * 2 + 1];
    float w0 = tok_prob[t * 2], w1 = tok_prob[t * 2 + 1];
    float4 a = reinterpret_cast<const float4*>(y + (size_t)p0 * Dd)[c];
    float4 b = reinterpret_cast<const float4*>(y + (size_t)p1 * Dd)[c];
    float4 o;
    o.x = w0 * a.x + w1 * b.x;
    o.y = w0 * a.y + w1 * b.y;
    o.z = w0 * a.z + w1 * b.z;
    o.w = w0 * a.w + w1 * b.w;
    reinterpret_cast<float4*>(out + (size_t)t * Dd)[c] = o;
}

// ---------------- host launch ----------------
extern "C" void kernel_launch(void* const* d_in, const int* in_sizes, int n_in,
                              void* d_out, int out_size, void* d_ws, size_t ws_size,
                              hipStream_t stream) {
    const float* x  = (const float*)d_in[0];
    const float* Wg = (const float*)d_in[1];
    const float* W1 = (const float*)d_in[2];
    const float* W2 = (const float*)d_in[3];
    const float* W3 = (const float*)d_in[4];
    float* out = (float*)d_out;

    char* ws = (char*)d_ws;
    size_t off = 0;
    auto alloc = [&](size_t bytes) -> char* {
        size_t o = off;
        off += (bytes + 255) & ~(size_t)255;
        return ws + o;
    };

    int* meta = (int*)alloc(64 * sizeof(int));
    int* tok_idx = (int*)alloc((size_t)TOK * 2 * sizeof(int));
    float* tok_prob = (float*)alloc((size_t)TOK * 2 * sizeof(float));
    int* pos_of = (int*)alloc((size_t)TOK * 2 * sizeof(int));
    int* list_tok = (int*)alloc((size_t)PAIRS * sizeof(int));
    float* list_prob = (float*)alloc((size_t)PAIRS * sizeof(float));
    unsigned short* xb = (unsigned short*)alloc((size_t)TOK * Dd * sizeof(unsigned short));
    unsigned short* hidden = (unsigned short*)alloc((size_t)PAIRS * Ff * sizeof(unsigned short));
    unsigned short* h1raw = (unsigned short*)alloc((size_t)PAIRS * Ff * sizeof(unsigned short));

    // bf16 weight copies; y (32 MB fp32) OVERLAYS W1b (32 MB bf16):
    // W1b read only in gemm1a; y written only in gemm2/combine (stream-ordered later).
    size_t wbytes = (size_t)Ee * Ff * Dd * sizeof(unsigned short);
    size_t ybytes = (size_t)PAIRS * Dd * sizeof(float);
    bool has_w = (ws_size >= off + 3 * wbytes + 4096);
    unsigned short *W1b = nullptr, *W2b = nullptr, *W3b = nullptr;
    float* y = nullptr;
    bool has_y = false;
    if (has_w) {
        W1b = (unsigned short*)alloc(wbytes);
        W2b = (unsigned short*)alloc(wbytes);
        W3b = (unsigned short*)alloc(wbytes);
        y = (float*)W1b;           // overlay
        has_y = true;
    } else if (ws_size >= off + ybytes + 4096) {
        y = (float*)alloc(ybytes);
        has_y = true;
    }

    // zero meta (out needs zeroing only in the no-y atomic fallback; here y always
    // exists on the proven ws budget, but keep the guard)
    int n4z = has_y ? 0 : out_size / 4;
    int zgrid = n4z > 0 ? (n4z + 255) / 256 : 1;
    zero_kernel<<<dim3(zgrid), dim3(256), 0, stream>>>(out, n4z, meta);

    gating_kernel<<<dim3(TOK / 4), dim3(256), 0, stream>>>(x, Wg, tok_idx, tok_prob, meta);
    scan_kernel<<<dim3(1), dim3(1), 0, stream>>>(meta);
    scatter_kernel<<<dim3(TOK / 256), dim3(256), 0, stream>>>(tok_idx, tok_prob, meta,
                                                              list_tok, list_prob, pos_of);

    int xn4 = TOK * Dd / 4;
    cvt_kernel<<<dim3((xn4 + 255) / 256), dim3(256), 0, stream>>>(x, xb, xn4);

    dim3 g1(Ff / 128, 32, Ee), g2(Dd / 128, 32, Ee), blk(256);

    if (has_w) {
        int wn4 = Ee * Ff * Dd / 4;
        cvt_kernel<<<dim3((wn4 + 255) / 256), blk, 0, stream>>>(W1, W1b, wn4);
        cvt_kernel<<<dim3((wn4 + 255) / 256), blk, 0, stream>>>(W2, W2b, wn4);
        cvt_kernel<<<dim3((wn4 + 255) / 256), blk, 0, stream>>>(W3, W3b, wn4);
        // gemm1a: h1 = x W1^T
        rgemm_kernel<unsigned short, 0><<<g1, blk, 0, stream>>>(
            xb, W1b, h1raw, nullptr, nullptr, list_tok, meta, Dd, Ff, 1);
        // gemm1b: hidden = silu(h1) * (x W2^T)
        rgemm_kernel<unsigned short, 1><<<g1, blk, 0, stream>>>(
            xb, W2b, h1raw, hidden, nullptr, list_tok, meta, Dd, Ff, 1);
        // gemm2: y = hidden W3^T
        rgemm_kernel<unsigned short, 2><<<g2, blk, 0, stream>>>(
            hidden, W3b, nullptr, nullptr, y, list_tok, meta, Ff, Dd, 0);
    } else {
        rgemm_kernel<float, 0><<<g1, blk, 0, stream>>>(
            xb, W1, h1raw, nullptr, nullptr, list_tok, meta, Dd, Ff, 1);
        rgemm_kernel<float, 1><<<g1, blk, 0, stream>>>(
            xb, W2, h1raw, hidden, nullptr, list_tok, meta, Dd, Ff, 1);
        rgemm_kernel<float, 2><<<g2, blk, 0, stream>>>(
            hidden, W3, nullptr, nullptr, y, list_tok, meta, Ff, Dd, 0);
    }

    if (has_y)
        combine_kernel<<<dim3(TOK * Dd / 4 / 256), blk, 0, stream>>>(y, pos_of, tok_prob, out);
}

// Round 5
// 472.154 us; speedup vs baseline: 3.0929x; 1.2612x over previous
//
#include <hip/hip_runtime.h>
#include <hip/hip_bf16.h>
#include <cstdint>

// MoE feed-forward, routed top-2 of 8 experts.
// B=2 S=2048 D=1024 F=2048 E=8 K=2.
// R5: kill atomic contention in routing. R4 counters: gating_kernel = top dispatch
//   at 105 us, VALUBusy 2.5%, HBM 1% -> 8192 device atomics on ONE cache line
//   (meta[0..7]). scatter_kernel had the same pathology on meta[8..15].
//   - gating: no atomics, writes tok_idx/tok_prob only
//   - route_kernel: single-block fused count+scan+scatter, zero global atomics,
//     register-private histograms + wave shuffle prefix sums (deterministic)
//   - rgemm (m97-shape single-acc, async global_load_lds) unchanged from R4

#define Dd 1024
#define Ff 2048
#define Ee 8
#define TOK 4096
#define PAIRS 8192

typedef __attribute__((ext_vector_type(8))) short short8;
typedef __attribute__((ext_vector_type(4))) float floatx4;

__device__ __forceinline__ unsigned short f2bf(float f) {
    unsigned int u = __float_as_uint(f);
    unsigned int r = (u + 0x7FFFu + ((u >> 16) & 1u)) >> 16;
    return (unsigned short)r;
}
__device__ __forceinline__ float bf2f(unsigned short u) {
    return __uint_as_float(((unsigned)u) << 16);
}

// async 16B/lane global->LDS. lds ptr is wave-uniform; lane i lands at lds + i*16B.
__device__ __forceinline__ void gload16(const unsigned short* g, unsigned short* l) {
    __builtin_amdgcn_global_load_lds(
        (const __attribute__((address_space(1))) unsigned int*)g,
        (__attribute__((address_space(3))) unsigned int*)l,
        16, 0, 0);
}

// ---------------- zero out (fallback path only) ----------------
__global__ void zero_kernel(float* __restrict__ out, int n4) {
    int i = blockIdx.x * blockDim.x + threadIdx.x;
    if (i < n4) reinterpret_cast<float4*>(out)[i] = make_float4(0.f, 0.f, 0.f, 0.f);
}

// ---------------- gating: fp32 scores, top-2, softmax (NO atomics) ----------------
__global__ void gating_kernel(const float* __restrict__ x, const float* __restrict__ Wg,
                              int* __restrict__ tok_idx, float* __restrict__ tok_prob) {
    int lane = threadIdx.x & 63;
    int w = threadIdx.x >> 6;
    int t = blockIdx.x * 4 + w;

    float xr[16];
    const float* xp = x + (size_t)t * Dd;
#pragma unroll
    for (int i = 0; i < 16; i++) xr[i] = xp[lane + i * 64];

    float sc[Ee];
    for (int e = 0; e < Ee; e++) {
        const float* wp = Wg + (size_t)e * Dd;
        float p = 0.f;
#pragma unroll
        for (int i = 0; i < 16; i++) p += xr[i] * wp[lane + i * 64];
        for (int off = 32; off > 0; off >>= 1) p += __shfl_xor(p, off);
        sc[e] = p;
    }
    if (lane == 0) {
        int e1 = 0, e2 = 0;
        float b1 = -1e30f, b2 = -1e30f;
        for (int e = 0; e < Ee; e++) {
            float s = sc[e];
            if (s > b1) { b2 = b1; e2 = e1; b1 = s; e1 = e; }
            else if (s > b2) { b2 = s; e2 = e; }
        }
        float p1 = 1.f / (1.f + expf(b2 - b1));
        float p2 = 1.f - p1;
        tok_idx[t * 2 + 0] = e1;
        tok_idx[t * 2 + 1] = e2;
        tok_prob[t * 2 + 0] = p1;
        tok_prob[t * 2 + 1] = p2;
    }
}

// ---------------- route: fused count + scan + stable scatter, one block ----------------
// 256 threads x 32 items = 8192 (t,k) assignments. No global atomics.
__global__ __launch_bounds__(256) void route_kernel(
    const int* __restrict__ tok_idx, const float* __restrict__ tok_prob,
    int* __restrict__ meta, int* __restrict__ list_tok,
    float* __restrict__ list_prob, int* __restrict__ pos_of) {
    int tid = threadIdx.x;
    int lane = tid & 63, w = tid >> 6;

    int e_loc[32];
#pragma unroll
    for (int j = 0; j < 32; j++) e_loc[j] = tok_idx[tid * 32 + j];

    // private histogram (static indexing only)
    int h[Ee];
#pragma unroll
    for (int e = 0; e < Ee; e++) {
        int c = 0;
#pragma unroll
        for (int j = 0; j < 32; j++) c += (e_loc[j] == e) ? 1 : 0;
        h[e] = c;
    }

    // per-expert exclusive prefix across the wave's 64 lanes + wave totals
    int pre[Ee], tot[Ee];
#pragma unroll
    for (int e = 0; e < Ee; e++) {
        int v = h[e];
        for (int d = 1; d < 64; d <<= 1) {
            int u = __shfl_up(v, d, 64);
            if (lane >= d) v += u;
        }
        pre[e] = v - h[e];
        tot[e] = __shfl(v, 63, 64);
    }

    __shared__ int wtot[4][Ee];
    __shared__ int wbase[4][Ee];
    __shared__ int ebase[Ee];
    if (lane == 0)
#pragma unroll
        for (int e = 0; e < Ee; e++) wtot[w][e] = tot[e];
    __syncthreads();
    if (tid == 0) {
        int etot[Ee];
        for (int e = 0; e < Ee; e++) {
            int s = 0;
            for (int ww = 0; ww < 4; ww++) { wbase[ww][e] = s; s += wtot[ww][e]; }
            etot[e] = s;
        }
        int b = 0;
        for (int e = 0; e < Ee; e++) {
            ebase[e] = b;
            meta[e] = etot[e];       // counts
            meta[16 + e] = b;        // bases
            b += etot[e];
        }
    }
    __syncthreads();

    int off[Ee];
#pragma unroll
    for (int e = 0; e < Ee; e++) off[e] = ebase[e] + wbase[w][e] + pre[e];

#pragma unroll
    for (int j = 0; j < 32; j++) {
        int item = tid * 32 + j;
        int el = e_loc[j];
        int pos = 0;
#pragma unroll
        for (int e = 0; e < Ee; e++) {
            if (el == e) { pos = off[e]; off[e] = pos + 1; }
        }
        list_tok[pos] = item >> 1;
        list_prob[pos] = tok_prob[item];
        pos_of[item] = pos;
    }
}

// ---------------- fp32 -> bf16 convert ----------------
__global__ void cvt_kernel(const float* __restrict__ src, unsigned short* __restrict__ dst, int n4) {
    int i = blockIdx.x * blockDim.x + threadIdx.x;
    if (i >= n4) return;
    float4 v = reinterpret_cast<const float4*>(src)[i];
    uint2 o;
    o.x = (unsigned)f2bf(v.x) | ((unsigned)f2bf(v.y) << 16);
    o.y = (unsigned)f2bf(v.z) | ((unsigned)f2bf(v.w) << 16);
    reinterpret_cast<uint2*>(dst)[i] = o;
}

// ---------------- manual fp32->bf16 LDS staging (fallback path only) ----------------
__device__ __forceinline__ void stage16(unsigned short* dst, const float* src) {
    const float4* s = reinterpret_cast<const float4*>(src);
    float4 v0 = s[0], v1 = s[1], v2 = s[2], v3 = s[3];
    uint4 o0, o1;
    o0.x = (unsigned)f2bf(v0.x) | ((unsigned)f2bf(v0.y) << 16);
    o0.y = (unsigned)f2bf(v0.z) | ((unsigned)f2bf(v0.w) << 16);
    o0.z = (unsigned)f2bf(v1.x) | ((unsigned)f2bf(v1.y) << 16);
    o0.w = (unsigned)f2bf(v1.z) | ((unsigned)f2bf(v1.w) << 16);
    o1.x = (unsigned)f2bf(v2.x) | ((unsigned)f2bf(v2.y) << 16);
    o1.y = (unsigned)f2bf(v2.z) | ((unsigned)f2bf(v2.w) << 16);
    o1.z = (unsigned)f2bf(v3.x) | ((unsigned)f2bf(v3.y) << 16);
    o1.w = (unsigned)f2bf(v3.z) | ((unsigned)f2bf(v3.w) << 16);
    uint4* d = reinterpret_cast<uint4*>(dst);
    d[0] = o0;
    d[1] = o1;
}

// ============ routed single-acc GEMM kernels (m97 shape) ============
// EPI: 0 = store bf16 C to h1raw
//      1 = read h1raw, hidden = silu(h1)*C (bf16)
//      2 = store fp32 C to y[pos]
template <typename WT, int EPI>
__global__ __launch_bounds__(256) void rgemm_kernel(
    const unsigned short* __restrict__ A,      // row source (xb or hidden), stride AK
    const WT* __restrict__ Bw,                 // weights, rows of length AK
    unsigned short* __restrict__ h1raw,        // EPI 0 write / EPI 1 read
    unsigned short* __restrict__ hout,         // EPI 1 write
    float* __restrict__ y,                     // EPI 2 write
    const int* __restrict__ list_tok, const int* __restrict__ meta,
    int AK, int BN, int arow_is_list) {
    constexpr bool BF = (sizeof(WT) == 2);
    int e = blockIdx.z;
    int cnt = meta[e];
    int m0 = blockIdx.y * 128;
    if (m0 >= cnt) return;
    int bs = meta[16 + e];
    int n0 = blockIdx.x * 128;

    __shared__ unsigned short sA[128 * 32];
    __shared__ unsigned short sB[128 * 32];

    int tid = threadIdx.x;
    int lane = tid & 63, w = tid >> 6;
    int wm = w >> 1, wn = w & 1;
    int lane15 = lane & 15, quad = lane >> 4;

    // async staging geometry: wave w stages rows [w*32, w*32+16) then +16
    int jr = w * 32 + (lane >> 2);
    int c8 = (lane & 3) * 8;
    unsigned short* ldsA0 = sA + w * 1024;
    unsigned short* ldsA1 = ldsA0 + 512;
    unsigned short* ldsB0 = sB + w * 1024;
    unsigned short* ldsB1 = ldsB0 + 512;

    int r0 = m0 + jr;      if (r0 >= cnt) r0 = cnt - 1;
    int r1 = m0 + jr + 16; if (r1 >= cnt) r1 = cnt - 1;
    size_t ar0 = arow_is_list ? (size_t)list_tok[bs + r0] : (size_t)(bs + r0);
    size_t ar1 = arow_is_list ? (size_t)list_tok[bs + r1] : (size_t)(bs + r1);
    const unsigned short* a0 = A + ar0 * AK + c8;
    const unsigned short* a1 = A + ar1 * AK + c8;

    const WT *b0 = nullptr, *b1 = nullptr, *bmp = nullptr;
    unsigned short* sBw = nullptr;
    if constexpr (BF) {
        b0 = Bw + ((size_t)e * BN + n0 + jr) * AK + c8;
        b1 = Bw + ((size_t)e * BN + n0 + jr + 16) * AK + c8;
    } else {
        int row = tid >> 1, colb = (tid & 1) * 16;
        bmp = Bw + ((size_t)e * BN + n0 + row) * AK + colb;
        sBw = &sB[row * 32 + colb];
    }

    const unsigned short* sAr = &sA[(wm * 64 + lane15) * 32 + quad * 8];
    const unsigned short* sBr = &sB[(wn * 64 + lane15) * 32 + quad * 8];

    floatx4 acc[4][4] = {};

    for (int k0 = 0; k0 < AK; k0 += 32) {
        gload16(a0 + k0, ldsA0);
        gload16(a1 + k0, ldsA1);
        if constexpr (BF) {
            gload16(b0 + k0, ldsB0);
            gload16(b1 + k0, ldsB1);
        } else {
            stage16(sBw, bmp + k0);
        }
        __syncthreads();
        short8 af[4], bfr[4];
#pragma unroll
        for (int i = 0; i < 4; i++) {
            af[i]  = *reinterpret_cast<const short8*>(sAr + i * 16 * 32);
            bfr[i] = *reinterpret_cast<const short8*>(sBr + i * 16 * 32);
        }
#pragma unroll
        for (int mi = 0; mi < 4; mi++)
#pragma unroll
            for (int ni = 0; ni < 4; ni++)
                acc[mi][ni] = __builtin_amdgcn_mfma_f32_16x16x32_bf16(af[mi], bfr[ni], acc[mi][ni], 0, 0, 0);
        __syncthreads();
    }

#pragma unroll
    for (int mi = 0; mi < 4; mi++) {
#pragma unroll
        for (int i = 0; i < 4; i++) {
            int rr = m0 + wm * 64 + mi * 16 + quad * 4 + i;
            if (rr < cnt) {
                int pos = bs + rr;
                if constexpr (EPI == 0) {
                    unsigned short* hp = h1raw + (size_t)pos * BN + n0 + wn * 64;
#pragma unroll
                    for (int ni = 0; ni < 4; ni++)
                        hp[ni * 16 + lane15] = f2bf(acc[mi][ni][i]);
                } else if constexpr (EPI == 1) {
                    const unsigned short* h1p = h1raw + (size_t)pos * BN + n0 + wn * 64;
                    unsigned short* hp = hout + (size_t)pos * BN + n0 + wn * 64;
#pragma unroll
                    for (int ni = 0; ni < 4; ni++) {
                        float h1 = bf2f(h1p[ni * 16 + lane15]);
                        float h2 = acc[mi][ni][i];
                        float hv = h1 / (1.f + expf(-h1)) * h2;
                        hp[ni * 16 + lane15] = f2bf(hv);
                    }
                } else {
                    float* yp = y + (size_t)pos * BN + n0 + wn * 64;
#pragma unroll
                    for (int ni = 0; ni < 4; ni++)
                        yp[ni * 16 + lane15] = acc[mi][ni][i];
                }
            }
        }
    }
}

// ---------------- combine: out[t] = p0*y[pos0] + p1*y[pos1] ----------------
__global__ void combine_kernel(const float* __restrict__ y,
                               const int* __restrict__ pos_of,
                               const float* __restrict__ tok_prob,
                               float* __restrict__ out) {
    int i = blockIdx.x * 256 + threadIdx.x;   // over TOK * Dd/4
    int t = i >> 8;                           // Dd/4 == 256
    int c = i & 255;
    int p0 = pos_of[t * 2], p1 = pos_of[t * 2 + 1];
    float w0 = tok_prob[t * 2], w1 = tok_prob[t * 2 + 1];
    float4 a = reinterpret_cast<const float4*>(y + (size_t)p0 * Dd)[c];
    float4 b = reinterpret_cast<const float4*>(y + (size_t)p1 * Dd)[c];
    float4 o;
    o.x = w0 * a.x + w1 * b.x;
    o.y = w0 * a.y + w1 * b.y;
    o.z = w0 * a.z + w1 * b.z;
    o.w = w0 * a.w + w1 * b.w;
    reinterpret_cast<float4*>(out + (size_t)t * Dd)[c] = o;
}

// ---------------- host launch ----------------
extern "C" void kernel_launch(void* const* d_in, const int* in_sizes, int n_in,
                              void* d_out, int out_size, void* d_ws, size_t ws_size,
                              hipStream_t stream) {
    const float* x  = (const float*)d_in[0];
    const float* Wg = (const float*)d_in[1];
    const float* W1 = (const float*)d_in[2];
    const float* W2 = (const float*)d_in[3];
    const float* W3 = (const float*)d_in[4];
    float* out = (float*)d_out;

    char* ws = (char*)d_ws;
    size_t off = 0;
    auto alloc = [&](size_t bytes) -> char* {
        size_t o = off;
        off += (bytes + 255) & ~(size_t)255;
        return ws + o;
    };

    int* meta = (int*)alloc(64 * sizeof(int));
    int* tok_idx = (int*)alloc((size_t)TOK * 2 * sizeof(int));
    float* tok_prob = (float*)alloc((size_t)TOK * 2 * sizeof(float));
    int* pos_of = (int*)alloc((size_t)TOK * 2 * sizeof(int));
    int* list_tok = (int*)alloc((size_t)PAIRS * sizeof(int));
    float* list_prob = (float*)alloc((size_t)PAIRS * sizeof(float));
    unsigned short* xb = (unsigned short*)alloc((size_t)TOK * Dd * sizeof(unsigned short));
    unsigned short* hidden = (unsigned short*)alloc((size_t)PAIRS * Ff * sizeof(unsigned short));
    unsigned short* h1raw = (unsigned short*)alloc((size_t)PAIRS * Ff * sizeof(unsigned short));

    // bf16 weight copies; y (32 MB fp32) OVERLAYS W1b (32 MB bf16):
    // W1b read only in gemm1a; y written only in gemm2/combine (stream-ordered later).
    size_t wbytes = (size_t)Ee * Ff * Dd * sizeof(unsigned short);
    size_t ybytes = (size_t)PAIRS * Dd * sizeof(float);
    bool has_w = (ws_size >= off + 3 * wbytes + 4096);
    unsigned short *W1b = nullptr, *W2b = nullptr, *W3b = nullptr;
    float* y = nullptr;
    bool has_y = false;
    if (has_w) {
        W1b = (unsigned short*)alloc(wbytes);
        W2b = (unsigned short*)alloc(wbytes);
        W3b = (unsigned short*)alloc(wbytes);
        y = (float*)W1b;           // overlay
        has_y = true;
    } else if (ws_size >= off + ybytes + 4096) {
        y = (float*)alloc(ybytes);
        has_y = true;
    }

    gating_kernel<<<dim3(TOK / 4), dim3(256), 0, stream>>>(x, Wg, tok_idx, tok_prob);
    route_kernel<<<dim3(1), dim3(256), 0, stream>>>(tok_idx, tok_prob, meta,
                                                    list_tok, list_prob, pos_of);

    int xn4 = TOK * Dd / 4;
    cvt_kernel<<<dim3((xn4 + 255) / 256), dim3(256), 0, stream>>>(x, xb, xn4);

    dim3 g1(Ff / 128, 32, Ee), g2(Dd / 128, 32, Ee), blk(256);

    if (has_w) {
        int wn4 = Ee * Ff * Dd / 4;
        cvt_kernel<<<dim3((wn4 + 255) / 256), blk, 0, stream>>>(W1, W1b, wn4);
        cvt_kernel<<<dim3((wn4 + 255) / 256), blk, 0, stream>>>(W2, W2b, wn4);
        cvt_kernel<<<dim3((wn4 + 255) / 256), blk, 0, stream>>>(W3, W3b, wn4);
        // gemm1a: h1 = x W1^T
        rgemm_kernel<unsigned short, 0><<<g1, blk, 0, stream>>>(
            xb, W1b, h1raw, nullptr, nullptr, list_tok, meta, Dd, Ff, 1);
        // gemm1b: hidden = silu(h1) * (x W2^T)
        rgemm_kernel<unsigned short, 1><<<g1, blk, 0, stream>>>(
            xb, W2b, h1raw, hidden, nullptr, list_tok, meta, Dd, Ff, 1);
        // gemm2: y = hidden W3^T
        rgemm_kernel<unsigned short, 2><<<g2, blk, 0, stream>>>(
            hidden, W3b, nullptr, nullptr, y, list_tok, meta, Ff, Dd, 0);
        combine_kernel<<<dim3(TOK * Dd / 4 / 256), blk, 0, stream>>>(y, pos_of, tok_prob, out);
    } else if (has_y) {
        rgemm_kernel<float, 0><<<g1, blk, 0, stream>>>(
            xb, W1, h1raw, nullptr, nullptr, list_tok, meta, Dd, Ff, 1);
        rgemm_kernel<float, 1><<<g1, blk, 0, stream>>>(
            xb, W2, h1raw, hidden, nullptr, list_tok, meta, Dd, Ff, 1);
        rgemm_kernel<float, 2><<<g2, blk, 0, stream>>>(
            hidden, W3, nullptr, nullptr, y, list_tok, meta, Ff, Dd, 0);
        combine_kernel<<<dim3(TOK * Dd / 4 / 256), blk, 0, stream>>>(y, pos_of, tok_prob, out);
    }
}